// Round 2
// baseline (691.358 us; speedup 1.0000x reference)
//
#include <hip/hip_runtime.h>
#include <hip/hip_bf16.h>

// out[n,m,d] = pw[l(m)] * sum_c x[n,m,c] * W[l(m)][c,d]
// N=50000, NCOMP=16, C=128. fp32 in/out (NaN in round 1 proved inputs are fp32,
// not bf16 — reading fp32 as bf16 makes NaN bit patterns). Threshold (2% of
// absmax) permits bf16 MFMA compute with fp32 accumulate.
//
// Structure: 16 per-component GEMMs [50000,128]x[128,128], MFMA 16x16x32 bf16.
// Pre-kernel bakes pw into bf16 transposed weights Wt[l][d][c] in d_ws (RNE),
// so B fragments are 16B bf16 loads (L1-resident, 32 KB per l). A fragments:
// fp32 loads from x, packed to bf16 in-register (round-to-nearest via +0x8000
// then v_perm_b32). No LDS, no __syncthreads.

using bf16 = __hip_bfloat16;
typedef short bf16x8 __attribute__((ext_vector_type(8)));  // MFMA A/B frag: 8 bf16 (4 VGPRs)
typedef float f32x4 __attribute__((ext_vector_type(4)));   // MFMA C/D frag

#define N_NODES 50000
#define NCOMP 16
#define C 128   // C_IN == C_OUT == 128

// Pack two fp32 -> one dword holding [bf16(lo) | bf16(hi)<<16], round-to-nearest.
__device__ inline unsigned pack2_bf16(float lo, float hi) {
    unsigned a = __float_as_uint(lo) + 0x8000u;
    unsigned b = __float_as_uint(hi) + 0x8000u;
    // result bytes (LSB..MSB): a.b2, a.b3, b.b2, b.b3
    return __builtin_amdgcn_perm(b, a, 0x07060302u);
}

// Wt[l][d][c] = bf16(pw[l] * W[l][c][d])   (65536 elements, 128 KB in d_ws)
__global__ void transpose_w_kernel(const float* __restrict__ W,
                                   const float* __restrict__ pw,
                                   bf16* __restrict__ Wt) {
    int idx = blockIdx.x * blockDim.x + threadIdx.x;  // 0..65535
    int l = idx >> 14;
    int rem = idx & 16383;
    int d = rem >> 7;
    int c = rem & 127;
    float v = W[(l << 14) + c * C + d] * pw[l];
    Wt[(l << 14) + d * C + c] = __float2bfloat16(v);  // RNE
}

__global__ __launch_bounds__(256) void linear_sh_kernel(const float* __restrict__ x,
                                                        const bf16* __restrict__ Wt,
                                                        float* __restrict__ out) {
    // block = (m, n-tile): m = bid & 15, tile = bid >> 4 covers n in [tile*128, +128)
    const int m    = blockIdx.x & 15;
    const int tile = blockIdx.x >> 4;
    const int l    = (m >= 9) ? 3 : (m >= 4) ? 2 : (m >= 1) ? 1 : 0;
    const bf16* __restrict__ wt = Wt + (l << 14);  // Wt[l][d][c], d-major

    const int wave = threadIdx.x >> 6;   // 4 waves: rows 32w..32w+31
    const int lane = threadIdx.x & 63;
    const int lrow = lane & 15;
    const int quad = lane >> 4;

    const int n_base = tile * 128 + wave * 32;

    f32x4 acc[2][8];
#pragma unroll
    for (int g = 0; g < 2; ++g)
#pragma unroll
        for (int c8 = 0; c8 < 8; ++c8)
            acc[g][c8] = (f32x4){0.f, 0.f, 0.f, 0.f};

    // A-fragment row base offsets (clamped for the n-tail; stores are guarded)
    long offA[2];
#pragma unroll
    for (int g = 0; g < 2; ++g) {
        int n = n_base + g * 16 + lrow;
        if (n >= N_NODES) n = N_NODES - 1;
        offA[g] = (long)(n * NCOMP + m) * C + quad * 8;  // elements; +kk*32 below
    }

    for (int kk = 0; kk < 4; ++kk) {  // K = 128 in 4 steps of 32
        bf16x8 a[2];
#pragma unroll
        for (int g = 0; g < 2; ++g) {
            const float4 f0 = *reinterpret_cast<const float4*>(x + offA[g] + kk * 32);
            const float4 f1 = *reinterpret_cast<const float4*>(x + offA[g] + kk * 32 + 4);
            union { unsigned u[4]; bf16x8 v; } pk;
            pk.u[0] = pack2_bf16(f0.x, f0.y);
            pk.u[1] = pack2_bf16(f0.z, f0.w);
            pk.u[2] = pack2_bf16(f1.x, f1.y);
            pk.u[3] = pack2_bf16(f1.z, f1.w);
            a[g] = pk.v;
        }
#pragma unroll
        for (int c8 = 0; c8 < 8; ++c8) {
            // B[k][col]: lane holds k = kk*32 + quad*8 + j, col = c8*16 + lrow
            bf16x8 b = *reinterpret_cast<const bf16x8*>(
                wt + (c8 * 16 + lrow) * C + kk * 32 + quad * 8);
            acc[0][c8] = __builtin_amdgcn_mfma_f32_16x16x32_bf16(a[0], b, acc[0][c8], 0, 0, 0);
            acc[1][c8] = __builtin_amdgcn_mfma_f32_16x16x32_bf16(a[1], b, acc[1][c8], 0, 0, 0);
        }
    }

    // Epilogue: D layout col = lane&15, row = quad*4 + reg. pw already in Wt.
#pragma unroll
    for (int g = 0; g < 2; ++g) {
#pragma unroll
        for (int r = 0; r < 4; ++r) {
            int n = n_base + g * 16 + quad * 4 + r;
            if (n < N_NODES) {
                long obase = (long)(n * NCOMP + m) * C;
#pragma unroll
                for (int c8 = 0; c8 < 8; ++c8)
                    out[obase + c8 * 16 + lrow] = acc[g][c8][r];
            }
        }
    }
}

extern "C" void kernel_launch(void* const* d_in, const int* in_sizes, int n_in,
                              void* d_out, int out_size, void* d_ws, size_t ws_size,
                              hipStream_t stream) {
    const float* x  = (const float*)d_in[0];   // [50000, 16, 128] fp32
    const float* W  = (const float*)d_in[1];   // [4, 128, 128] fp32
    const float* pw = (const float*)d_in[2];   // [4] fp32
    float* out = (float*)d_out;                // [50000, 16, 128] fp32
    bf16* Wt  = (bf16*)d_ws;                   // 65536 bf16 = 128 KB scratch

    // Wt[l][d][c] = bf16(pw[l] * W[l][c][d])
    transpose_w_kernel<<<256, 256, 0, stream>>>(W, pw, Wt);

    const int tiles = (N_NODES + 127) / 128;  // 391
    linear_sh_kernel<<<tiles * NCOMP, 256, 0, stream>>>(x, Wt, out);
}